// Round 2
// baseline (323.931 us; speedup 1.0000x reference)
//
#include <hip/hip_runtime.h>
#include <cmath>

// Problem constants (fixed by the reference)
#define BB   64
#define TT   4096
#define DD1  256
#define DD2  128
#define UU   64
#define NT   16      // T tiles per batch row
#define TTILE 256    // rows per block
#define CH   64      // rows per chunk (staged in LDS)
#define LDA  260     // padded leading dim of A tile (floats): breaks bank conflicts

// LDS layout (float offsets)
#define A_OFF    0                      // 64 x 260 = 16640
#define W1_OFF   16640                  // 256 x 64 = 16384
#define BIAS_OFF 33024                  // 64
#define W_OFF    33088                  // 64  (per-chunk softmax weights)
#define LOG_OFF  33152                  // 64  (per-chunk logits)
#define ML_OFF   33216                  // [0]=m, [1]=l, [2]=rescale, [3]=pad
#define RED_OFF  33220                  // 1024 (bias partials / final acc combine)
#define LDS_FLOATS 34244                // 136,976 B  (< 160 KiB/CU)

__device__ __forceinline__ float tanh_fast(float x) {
    // tanh(x) = sign(x) * (1 - e^{-2|x|}) / (1 + e^{-2|x|}); overflow-safe
    float ax = fabsf(x);
    float e  = __expf(-2.0f * ax);
    float t  = __fdividef(1.0f - e, 1.0f + e);
    return x < 0.0f ? -t : t;
}

__global__ __launch_bounds__(256)
void caa_main(const float* __restrict__ seq, const float* __restrict__ ctx,
              const float* __restrict__ W1, const float* __restrict__ W2,
              float* __restrict__ part) {
    extern __shared__ __align__(16) float lds[];
    const int tid  = threadIdx.x;
    const int bx   = blockIdx.x;
    const int b    = bx >> 4;        // batch
    const int tile = bx & 15;        // T tile
    const int tx   = tid & 15;       // u-group (4 u each)
    const int ty   = tid >> 4;       // t-group (4 t each)
    const int wv   = tid >> 6;       // wave index 0..3
    const int q    = tid & 63;       // lane

    const float* seqbase = seq + ((size_t)b * TT + (size_t)tile * TTILE) * DD1;

    // ---- stage W1_seq (256x64 fp32 = 64 KiB) into LDS, row-major [k][u] ----
    {
        const float4* g = (const float4*)W1;          // W1[:256] is W1_seq
        float4*       s = (float4*)&lds[W1_OFF];
        #pragma unroll
        for (int i = 0; i < 16; ++i) s[i * 256 + tid] = g[i * 256 + tid];
    }
    // ---- bias partials: bias[u] = sum_c ctx[b][c] * W1[256+c][u], split c into 4 ----
    {
        const int u  = tid & 63;
        const int cq = tid >> 6;                       // c-chunk 0..3 (32 c each)
        float s = 0.0f;
        const float* cb = ctx + b * DD2 + cq * 32;
        const float* wb = W1 + (size_t)(DD1 + cq * 32) * UU + u;
        #pragma unroll 8
        for (int c = 0; c < 32; ++c) s = fmaf(cb[c], wb[c * UU], s);
        lds[RED_OFF + cq * 64 + u] = s;
    }
    if (tid == 0) { lds[ML_OFF] = -INFINITY; lds[ML_OFF + 1] = 0.0f; }

    // ---- prefetch chunk 0 into registers (coalesced float4; 16/thread = full 64 rows) ----
    // float4 index f = j*256 + tid = j*256 + 64*wv + q  ->  row f/64 = 4j+wv, col (f%64)*4 = 4q
    float4 pf[16];
    {
        const float4* g = (const float4*)seqbase;
        #pragma unroll
        for (int j = 0; j < 16; ++j) pf[j] = g[j * 256 + tid];
    }
    __syncthreads();
    // bias reduce (4 partials -> bias[u])
    if (tid < 64) {
        lds[BIAS_OFF + tid] = lds[RED_OFF + tid] + lds[RED_OFF + 64 + tid]
                            + lds[RED_OFF + 128 + tid] + lds[RED_OFF + 192 + tid];
    }
    // write chunk 0 to LDS A tile
    {
        const int q4 = q * 4;
        #pragma unroll
        for (int j = 0; j < 16; ++j)
            *(float4*)&lds[A_OFF + (4 * j + wv) * LDA + q4] = pf[j];
    }
    __syncthreads();

    const float4 w2v   = *(const float4*)(W2 + 4 * tx);
    float4 acc4 = make_float4(0.f, 0.f, 0.f, 0.f);     // weighted-sum acc, d = q*4..q*4+3, t-quarter wv

    for (int c = 0; c < 4; ++c) {
        // issue global prefetch for next chunk (hidden under GEMM)
        if (c < 3) {
            const float4* g = (const float4*)(seqbase + (size_t)(c + 1) * CH * DD1);
            #pragma unroll
            for (int j = 0; j < 16; ++j) pf[j] = g[j * 256 + tid];
        }
        // ---- register-tiled GEMM: 4t x 4u per thread, K=256 ----
        float accm[4][4] = {{0.f}};
        const float* Ab = &lds[A_OFF + (4 * ty) * LDA];
        const float* Bb = &lds[W1_OFF + 4 * tx];
        #pragma unroll 2
        for (int k0 = 0; k0 < 256; k0 += 4) {
            float4 b0 = *(const float4*)(Bb + (k0 + 0) * 64);
            float4 b1 = *(const float4*)(Bb + (k0 + 1) * 64);
            float4 b2 = *(const float4*)(Bb + (k0 + 2) * 64);
            float4 b3 = *(const float4*)(Bb + (k0 + 3) * 64);
            #pragma unroll
            for (int i = 0; i < 4; ++i) {
                float4 a = *(const float4*)(Ab + i * LDA + k0);
                accm[i][0] = fmaf(a.x, b0.x, fmaf(a.y, b1.x, fmaf(a.z, b2.x, fmaf(a.w, b3.x, accm[i][0]))));
                accm[i][1] = fmaf(a.x, b0.y, fmaf(a.y, b1.y, fmaf(a.z, b2.y, fmaf(a.w, b3.y, accm[i][1]))));
                accm[i][2] = fmaf(a.x, b0.z, fmaf(a.y, b1.z, fmaf(a.z, b2.z, fmaf(a.w, b3.z, accm[i][2]))));
                accm[i][3] = fmaf(a.x, b0.w, fmaf(a.y, b1.w, fmaf(a.z, b2.w, fmaf(a.w, b3.w, accm[i][3]))));
            }
        }
        // ---- epilogue: tanh + W2 dot + reduce over the 16 tx lanes ----
        const float4 bias4 = *(const float4*)&lds[BIAS_OFF + 4 * tx];
        float lp[4];
        #pragma unroll
        for (int i = 0; i < 4; ++i) {
            float e0 = tanh_fast(accm[i][0] + bias4.x);
            float e1 = tanh_fast(accm[i][1] + bias4.y);
            float e2 = tanh_fast(accm[i][2] + bias4.z);
            float e3 = tanh_fast(accm[i][3] + bias4.w);
            float p  = e0 * w2v.x + e1 * w2v.y + e2 * w2v.z + e3 * w2v.w;
            p += __shfl_xor(p, 1, 64);
            p += __shfl_xor(p, 2, 64);
            p += __shfl_xor(p, 4, 64);
            p += __shfl_xor(p, 8, 64);
            lp[i] = p;
        }
        if (tx == 0) {
            #pragma unroll
            for (int i = 0; i < 4; ++i) lds[LOG_OFF + 4 * ty + i] = lp[i];
        }
        __syncthreads();
        // ---- online softmax update (wave 0) ----
        if (tid < 64) {
            float lg = lds[LOG_OFF + tid];
            float mx = lg;
            mx = fmaxf(mx, __shfl_xor(mx, 1, 64));
            mx = fmaxf(mx, __shfl_xor(mx, 2, 64));
            mx = fmaxf(mx, __shfl_xor(mx, 4, 64));
            mx = fmaxf(mx, __shfl_xor(mx, 8, 64));
            mx = fmaxf(mx, __shfl_xor(mx, 16, 64));
            mx = fmaxf(mx, __shfl_xor(mx, 32, 64));
            float mold = lds[ML_OFF];
            float mnew = fmaxf(mold, mx);
            float r    = __expf(mold - mnew);        // first chunk: exp(-inf) = 0
            float w    = __expf(lg - mnew);
            float s    = w;
            s += __shfl_xor(s, 1, 64);
            s += __shfl_xor(s, 2, 64);
            s += __shfl_xor(s, 4, 64);
            s += __shfl_xor(s, 8, 64);
            s += __shfl_xor(s, 16, 64);
            s += __shfl_xor(s, 32, 64);
            lds[W_OFF + tid] = w;
            if (tid == 0) {
                lds[ML_OFF]     = mnew;
                lds[ML_OFF + 1] = lds[ML_OFF + 1] * r + s;
                lds[ML_OFF + 2] = r;
            }
        }
        __syncthreads();
        // ---- weighted accumulation from LDS A tile (wave wv owns t in [16wv,16wv+16)) ----
        {
            float r = lds[ML_OFF + 2];
            acc4.x *= r; acc4.y *= r; acc4.z *= r; acc4.w *= r;
            const float* Aacc = &lds[A_OFF + (wv * 16) * LDA + q * 4];
            #pragma unroll
            for (int t4 = 0; t4 < 16; t4 += 4) {
                float4 wq = *(const float4*)&lds[W_OFF + wv * 16 + t4];
                float4 a0 = *(const float4*)(Aacc + (t4 + 0) * LDA);
                float4 a1 = *(const float4*)(Aacc + (t4 + 1) * LDA);
                float4 a2 = *(const float4*)(Aacc + (t4 + 2) * LDA);
                float4 a3 = *(const float4*)(Aacc + (t4 + 3) * LDA);
                acc4.x = fmaf(wq.x, a0.x, acc4.x); acc4.y = fmaf(wq.x, a0.y, acc4.y);
                acc4.z = fmaf(wq.x, a0.z, acc4.z); acc4.w = fmaf(wq.x, a0.w, acc4.w);
                acc4.x = fmaf(wq.y, a1.x, acc4.x); acc4.y = fmaf(wq.y, a1.y, acc4.y);
                acc4.z = fmaf(wq.y, a1.z, acc4.z); acc4.w = fmaf(wq.y, a1.w, acc4.w);
                acc4.x = fmaf(wq.z, a2.x, acc4.x); acc4.y = fmaf(wq.z, a2.y, acc4.y);
                acc4.z = fmaf(wq.z, a2.z, acc4.z); acc4.w = fmaf(wq.z, a2.w, acc4.w);
                acc4.x = fmaf(wq.w, a3.x, acc4.x); acc4.y = fmaf(wq.w, a3.y, acc4.y);
                acc4.z = fmaf(wq.w, a3.z, acc4.z); acc4.w = fmaf(wq.w, a3.w, acc4.w);
            }
        }
        __syncthreads();   // done reading A tile
        if (c < 3) {
            const int q4 = q * 4;
            #pragma unroll
            for (int j = 0; j < 16; ++j)
                *(float4*)&lds[A_OFF + (4 * j + wv) * LDA + q4] = pf[j];
            __syncthreads();
        }
    }

    // ---- combine 4 per-wave t-partials and write the (b,tile) partial record ----
    {
        float4* red = (float4*)&lds[RED_OFF];
        red[wv * 64 + q] = acc4;
    }
    __syncthreads();
    {
        float f = lds[RED_OFF + tid] + lds[RED_OFF + 256 + tid]
                + lds[RED_OFF + 512 + tid] + lds[RED_OFF + 768 + tid];
        size_t base = (size_t)bx * 258;
        part[base + tid] = f;
        if (tid == 0) part[base + 256] = lds[ML_OFF];
        if (tid == 1) part[base + 257] = lds[ML_OFF + 1];
    }
}

__global__ __launch_bounds__(256)
void caa_combine(const float* __restrict__ part, float* __restrict__ out) {
    const int b = blockIdx.x, tid = threadIdx.x;
    __shared__ float sm[NT], sl[NT];
    if (tid < NT) {
        sm[tid] = part[(size_t)(b * NT + tid) * 258 + 256];
        sl[tid] = part[(size_t)(b * NT + tid) * 258 + 257];
    }
    __syncthreads();
    float M = sm[0];
    #pragma unroll
    for (int i = 1; i < NT; ++i) M = fmaxf(M, sm[i]);
    float S = 0.0f, o = 0.0f;
    #pragma unroll
    for (int i = 0; i < NT; ++i) {
        float e = __expf(sm[i] - M);
        S = fmaf(sl[i], e, S);
        o = fmaf(e, part[(size_t)(b * NT + i) * 258 + tid], o);
    }
    out[b * 256 + tid] = __fdividef(o, S);
}

extern "C" void kernel_launch(void* const* d_in, const int* in_sizes, int n_in,
                              void* d_out, int out_size, void* d_ws, size_t ws_size,
                              hipStream_t stream) {
    const float* seq = (const float*)d_in[0];
    const float* ctx = (const float*)d_in[1];
    const float* W1  = (const float*)d_in[2];
    const float* W2  = (const float*)d_in[3];
    float* part = (float*)d_ws;   // needs NT*BB*258*4 = 1,056,768 B of scratch

    // >64 KiB dynamic LDS requires the opt-in attribute (idempotent host call,
    // not stream-ordered -> safe under graph capture)
    (void)hipFuncSetAttribute((const void*)caa_main,
                              hipFuncAttributeMaxDynamicSharedMemorySize,
                              LDS_FLOATS * 4);

    caa_main<<<dim3(BB * NT), dim3(256), LDS_FLOATS * 4, stream>>>(seq, ctx, W1, W2, part);
    caa_combine<<<dim3(BB), dim3(256), 0, stream>>>(part, (float*)d_out);
}

// Round 3
// 87.927 us; speedup vs baseline: 3.6841x; 3.6841x over previous
//
#include <hip/hip_runtime.h>
#include <cmath>

// Problem constants (fixed by the reference)
#define BB   64
#define TT   4096
#define DD1  256
#define DD2  128
#define UU   64
#define NT   16      // T tiles per batch row
#define TTILE 256    // rows per block
#define CH   64      // rows per chunk (staged in LDS)
#define NCH  4
#define THREADS 512

// A/W1T rows are 264 bf16 (=528 B): row-to-row bank rotation of 4 dwords,
// 16B-aligned (528 % 16 == 0) so ds_read_b128 frags are legal and ~2-way.
#define ROWB 528
#define HL   33792   // byte delta hi-array -> lo-array

// LDS byte offsets
#define AH_OFF   0        // A hi  [64][264] bf16 = 33792 B
#define AL_OFF   33792    // A lo
#define WH_OFF   67584    // W1T hi [64 u][264 k] bf16
#define WL_OFF   101376   // W1T lo
#define BIAS_OFF 135168   // 64 f32
#define WCH_OFF  135424   // 64 f32 per-chunk softmax weights
#define LOGP_OFF 135680   // 128 f32 logit partials (2 u-halves x 64 rows)
#define ML_OFF   136192   // [0]=m [1]=l [2]=rescale [3]=pad
#define RED_OFF  136208   // 1024 f32 (bias partials / final acc combine)
#define LDS_BYTES 140304  // < 160 KiB

typedef short bf16x8 __attribute__((ext_vector_type(8)));
typedef float f32x4  __attribute__((ext_vector_type(4)));

__device__ __forceinline__ float tanh_fast(float x) {
    float ax = fabsf(x);
    float e  = __expf(-2.0f * ax);
    float t  = __fdividef(1.0f - e, 1.0f + e);
    return x < 0.0f ? -t : t;
}

// Convert float4 -> bf16 hi/lo pairs and store 8B each to A_hi / A_lo.
__device__ __forceinline__ void cvt_write_row(char* smem, int row, int c4, float4 a) {
    unsigned b0 = __float_as_uint(a.x), b1 = __float_as_uint(a.y);
    unsigned b2 = __float_as_uint(a.z), b3 = __float_as_uint(a.w);
    unsigned h01 = (b0 >> 16) | (b1 & 0xffff0000u);
    unsigned h23 = (b2 >> 16) | (b3 & 0xffff0000u);
    float d0 = a.x - __uint_as_float(b0 & 0xffff0000u);
    float d1 = a.y - __uint_as_float(b1 & 0xffff0000u);
    float d2 = a.z - __uint_as_float(b2 & 0xffff0000u);
    float d3 = a.w - __uint_as_float(b3 & 0xffff0000u);
    unsigned l01 = (__float_as_uint(d0) >> 16) | (__float_as_uint(d1) & 0xffff0000u);
    unsigned l23 = (__float_as_uint(d2) >> 16) | (__float_as_uint(d3) & 0xffff0000u);
    *(uint2*)(smem + AH_OFF + row * ROWB + c4 * 8) = make_uint2(h01, h23);
    *(uint2*)(smem + AL_OFF + row * ROWB + c4 * 8) = make_uint2(l01, l23);
}

__global__ __launch_bounds__(THREADS, 2)   // force VGPR<=256: 8 waves/block MUST fit 2/SIMD
void caa_main(const float* __restrict__ seq, const float* __restrict__ ctx,
              const float* __restrict__ W1, const float* __restrict__ W2,
              float* __restrict__ part) {
    extern __shared__ __align__(16) char smem[];
    float* fml   = (float*)(smem + ML_OFF);
    float* fbias = (float*)(smem + BIAS_OFF);
    float* fwch  = (float*)(smem + WCH_OFF);
    float* flogp = (float*)(smem + LOGP_OFF);
    float* fred  = (float*)(smem + RED_OFF);

    const int tid = threadIdx.x;
    const int bx  = blockIdx.x;
    const int b    = bx >> 4, tile = bx & 15;
    const int w    = tid >> 6, l = tid & 63;
    const int l15  = l & 15,  kg = l >> 4;     // MFMA: input row/col = l15, k-group = kg
    const int mf   = w & 3,   nh = w >> 2;     // wave -> m-frag (16 rows), u-half (32 u)

    const float* seqbase = seq + ((size_t)b * TT + (size_t)tile * TTILE) * DD1;

    // ---- chunk 0 global prefetch (8 float4 = 32 VGPR, no spill) ----
    float4 pf[8];
    {
        const float4* g = (const float4*)seqbase;
        #pragma unroll
        for (int j = 0; j < 8; ++j) pf[j] = g[j * THREADS + tid];
    }

    // ---- W1T hi/lo staging: [k][u] fp32 -> [u][k] bf16 hi/lo (one-time) ----
    {
        const float4* g = (const float4*)W1;
        unsigned short* WH = (unsigned short*)(smem + WH_OFF);
        unsigned short* WL = (unsigned short*)(smem + WL_OFF);
        #pragma unroll
        for (int j = 0; j < 8; ++j) {
            int f = j * THREADS + tid;
            int k = f >> 4, u4 = (f & 15) * 4;
            float4 a = g[f];
            float v[4] = {a.x, a.y, a.z, a.w};
            #pragma unroll
            for (int i = 0; i < 4; ++i) {
                unsigned bv = __float_as_uint(v[i]);
                float hf = __uint_as_float(bv & 0xffff0000u);
                unsigned lo = __float_as_uint(v[i] - hf) >> 16;
                WH[(u4 + i) * 264 + k] = (unsigned short)(bv >> 16);
                WL[(u4 + i) * 264 + k] = (unsigned short)lo;
            }
        }
    }
    // ---- bias partials: 8 c-chunks x 64 u ----
    {
        int cq = tid >> 6;
        float s = 0.f;
        const float* cb = ctx + b * DD2 + cq * 16;
        const float* wb = W1 + (size_t)(DD1 + cq * 16) * UU + l;
        #pragma unroll
        for (int c = 0; c < 16; ++c) s = fmaf(cb[c], wb[c * UU], s);
        fred[cq * 64 + l] = s;
    }
    if (tid == 0) { fml[0] = -INFINITY; fml[1] = 0.f; }

    // ---- chunk 0 convert + LDS write ----
    {
        const int c4 = tid & 63, rb = tid >> 6;
        #pragma unroll
        for (int j = 0; j < 8; ++j) cvt_write_row(smem, j * 8 + rb, c4, pf[j]);
    }
    __syncthreads();
    if (tid < 64) {
        float s = 0.f;
        #pragma unroll
        for (int cq = 0; cq < 8; ++cq) s += fred[cq * 64 + tid];
        fbias[tid] = s;
    }
    __syncthreads();

    const int u0g = nh * 32 + l15, u1g = u0g + 16;
    const float bias0 = fbias[u0g], bias1 = fbias[u1g];
    const float w20 = W2[u0g], w21 = W2[u1g];

    const int aB  = AH_OFF + (16 * mf + l15) * ROWB + kg * 16;
    const int b0B = WH_OFF + u0g * ROWB + kg * 16;
    const int b1B = WH_OFF + u1g * ROWB + kg * 16;

    float2 acc2 = make_float2(0.f, 0.f);          // weighted-sum acc: dims d0,d0+1, t-quarter tq
    const int dp = tid & 127, tq = tid >> 7;
    const int d0 = dp * 2;

    for (int c = 0; c < NCH; ++c) {
        if (c < NCH - 1) {   // issue next-chunk loads; consumed only after 3 barriers
            const float4* g = (const float4*)(seqbase + (size_t)(c + 1) * CH * DD1);
            #pragma unroll
            for (int j = 0; j < 8; ++j) pf[j] = g[j * THREADS + tid];
        }
        // ---- split-bf16 MFMA GEMM: E = A*W1seq, 64x64 tile, K=256 ----
        f32x4 acc0 = {0.f, 0.f, 0.f, 0.f}, acc1 = {0.f, 0.f, 0.f, 0.f};
        #pragma unroll
        for (int ks = 0; ks < 8; ++ks) {
            const int off = ks * 64;
            bf16x8 ah  = *(const bf16x8*)(smem + aB + off);
            bf16x8 al  = *(const bf16x8*)(smem + aB + HL + off);
            bf16x8 b0h = *(const bf16x8*)(smem + b0B + off);
            bf16x8 b0l = *(const bf16x8*)(smem + b0B + HL + off);
            bf16x8 b1h = *(const bf16x8*)(smem + b1B + off);
            bf16x8 b1l = *(const bf16x8*)(smem + b1B + HL + off);
            acc0 = __builtin_amdgcn_mfma_f32_16x16x32_bf16(ah, b0h, acc0, 0, 0, 0);
            acc1 = __builtin_amdgcn_mfma_f32_16x16x32_bf16(ah, b1h, acc1, 0, 0, 0);
            acc0 = __builtin_amdgcn_mfma_f32_16x16x32_bf16(ah, b0l, acc0, 0, 0, 0);
            acc1 = __builtin_amdgcn_mfma_f32_16x16x32_bf16(ah, b1l, acc1, 0, 0, 0);
            acc0 = __builtin_amdgcn_mfma_f32_16x16x32_bf16(al, b0h, acc0, 0, 0, 0);
            acc1 = __builtin_amdgcn_mfma_f32_16x16x32_bf16(al, b1h, acc1, 0, 0, 0);
        }
        // ---- epilogue: tanh + W2 dot; reduce over u (lane&15) ----
        float lp[4];
        #pragma unroll
        for (int r = 0; r < 4; ++r) {
            float e0 = tanh_fast(acc0[r] + bias0);
            float e1 = tanh_fast(acc1[r] + bias1);
            float p  = e0 * w20 + e1 * w21;
            p += __shfl_xor(p, 1, 64);
            p += __shfl_xor(p, 2, 64);
            p += __shfl_xor(p, 4, 64);
            p += __shfl_xor(p, 8, 64);
            lp[r] = p;
        }
        if (l15 == 0) {      // C/D row = kg*4 + r within m-frag (m89-verified layout)
            #pragma unroll
            for (int r = 0; r < 4; ++r) flogp[nh * 64 + 16 * mf + kg * 4 + r] = lp[r];
        }
        __syncthreads();
        // ---- online softmax over the 64 chunk rows (wave 0) ----
        if (tid < 64) {
            float lg = flogp[tid] + flogp[64 + tid];
            float mx = lg;
            mx = fmaxf(mx, __shfl_xor(mx, 1, 64));
            mx = fmaxf(mx, __shfl_xor(mx, 2, 64));
            mx = fmaxf(mx, __shfl_xor(mx, 4, 64));
            mx = fmaxf(mx, __shfl_xor(mx, 8, 64));
            mx = fmaxf(mx, __shfl_xor(mx, 16, 64));
            mx = fmaxf(mx, __shfl_xor(mx, 32, 64));
            float mold = fml[0];
            float mnew = fmaxf(mold, mx);
            float rsc  = __expf(mold - mnew);     // first chunk: exp(-inf)=0
            float wv   = __expf(lg - mnew);
            float ss   = wv;
            ss += __shfl_xor(ss, 1, 64);
            ss += __shfl_xor(ss, 2, 64);
            ss += __shfl_xor(ss, 4, 64);
            ss += __shfl_xor(ss, 8, 64);
            ss += __shfl_xor(ss, 16, 64);
            ss += __shfl_xor(ss, 32, 64);
            fwch[tid] = wv;
            if (tid == 0) { fml[0] = mnew; fml[1] = fml[1] * rsc + ss; fml[2] = rsc; }
        }
        __syncthreads();
        // ---- weighted accumulation (reconstruct f32 = bf16hi + bf16lo) ----
        {
            float rsc = fml[2];
            acc2.x *= rsc; acc2.y *= rsc;
            #pragma unroll
            for (int i = 0; i < 16; ++i) {
                int row = tq * 16 + i;
                float wr = fwch[row];
                unsigned h  = *(const unsigned*)(smem + AH_OFF + row * ROWB + d0 * 2);
                unsigned lo = *(const unsigned*)(smem + AL_OFF + row * ROWB + d0 * 2);
                float f0 = __uint_as_float(h << 16) + __uint_as_float(lo << 16);
                float f1 = __uint_as_float(h & 0xffff0000u) + __uint_as_float(lo & 0xffff0000u);
                acc2.x = fmaf(wr, f0, acc2.x);
                acc2.y = fmaf(wr, f1, acc2.y);
            }
        }
        __syncthreads();    // done reading A tile
        if (c < NCH - 1) {
            const int c4 = tid & 63, rb = tid >> 6;
            #pragma unroll
            for (int j = 0; j < 8; ++j) cvt_write_row(smem, j * 8 + rb, c4, pf[j]);
            __syncthreads();
        }
    }

    // ---- combine 4 t-quarters, write (b,tile) partial record ----
    *(float2*)&fred[tq * 256 + d0] = acc2;
    __syncthreads();
    if (tid < 256) {
        float s = fred[tid] + fred[256 + tid] + fred[512 + tid] + fred[768 + tid];
        size_t base = (size_t)bx * 258;
        part[base + tid] = s;
        if (tid == 0) part[base + 256] = fml[0];
        if (tid == 1) part[base + 257] = fml[1];
    }
}

__global__ __launch_bounds__(256)
void caa_combine(const float* __restrict__ part, float* __restrict__ out) {
    const int b = blockIdx.x, tid = threadIdx.x;
    __shared__ float sm[NT], sl[NT];
    if (tid < NT) {
        sm[tid] = part[(size_t)(b * NT + tid) * 258 + 256];
        sl[tid] = part[(size_t)(b * NT + tid) * 258 + 257];
    }
    __syncthreads();
    float M = sm[0];
    #pragma unroll
    for (int i = 1; i < NT; ++i) M = fmaxf(M, sm[i]);
    float S = 0.0f, o = 0.0f;
    #pragma unroll
    for (int i = 0; i < NT; ++i) {
        float e = __expf(sm[i] - M);
        S = fmaf(sl[i], e, S);
        o = fmaf(e, part[(size_t)(b * NT + i) * 258 + tid], o);
    }
    out[b * 256 + tid] = __fdividef(o, S);
}

extern "C" void kernel_launch(void* const* d_in, const int* in_sizes, int n_in,
                              void* d_out, int out_size, void* d_ws, size_t ws_size,
                              hipStream_t stream) {
    const float* seq = (const float*)d_in[0];
    const float* ctx = (const float*)d_in[1];
    const float* W1  = (const float*)d_in[2];
    const float* W2  = (const float*)d_in[3];
    float* part = (float*)d_ws;   // NT*BB*258*4 = 1,056,768 B of scratch

    (void)hipFuncSetAttribute((const void*)caa_main,
                              hipFuncAttributeMaxDynamicSharedMemorySize,
                              LDS_BYTES);

    caa_main<<<dim3(BB * NT), dim3(THREADS), LDS_BYTES, stream>>>(seq, ctx, W1, W2, part);
    caa_combine<<<dim3(BB), dim3(256), 0, stream>>>(part, (float*)d_out);
}